// Round 1
// 370.141 us; speedup vs baseline: 1.1913x; 1.1913x over previous
//
#include <hip/hip_runtime.h>

#define NEG_SLOPE 0.01f
#define BSHIFT 8          // nodes per dst-bucket = 256
#define BMASK 255
#define BMAX 512          // LDS histogram capacity (supports N <= 131072)

typedef __attribute__((ext_vector_type(8))) short bf16x8;
typedef __attribute__((ext_vector_type(4))) float f32x4;

// fp32 -> bf16 (RNE, normals only — fine for this data)
static __device__ inline unsigned short f2b(float f) {
    unsigned u = __builtin_bit_cast(unsigned, f);
    return (unsigned short)((u + 0x7FFF + ((u >> 16) & 1)) >> 16);
}
static __device__ inline float b2f_lo(unsigned u) {
    return __builtin_bit_cast(float, u << 16);
}
static __device__ inline float b2f_hi(unsigned u) {
    return __builtin_bit_cast(float, u & 0xFFFF0000u);
}

// ---------------------------------------------------------------------------
// feat fp32 -> bf16 (N*128 elements, multiple of 4)
// ---------------------------------------------------------------------------
__global__ __launch_bounds__(256) void cvt_feat(const float* __restrict__ x,
                                                unsigned short* __restrict__ xb,
                                                long long n) {
    long long i = ((long long)blockIdx.x * 256 + threadIdx.x) * 4;
    if (i < n) {
        float4 v = *(const float4*)(x + i);
        ushort4 o;
        o.x = f2b(v.x); o.y = f2b(v.y); o.z = f2b(v.z); o.w = f2b(v.w);
        *(ushort4*)(xb + i) = o;
    }
}

// ---------------------------------------------------------------------------
// W[k][n] fp32 -> Wt[n][k] bf16, both layers (128x128 each; tiny one-time cost)
// ---------------------------------------------------------------------------
__global__ __launch_bounds__(256) void cvt_w(const float* __restrict__ W1,
                                             const float* __restrict__ W2,
                                             unsigned short* __restrict__ Wt1,
                                             unsigned short* __restrict__ Wt2) {
    int i = blockIdx.x * 256 + threadIdx.x;   // 0..16383
    int n = i & 127, k = i >> 7;
    Wt1[n * 128 + k] = f2b(W1[k * 128 + n]);
    Wt2[n * 128 + k] = f2b(W2[k * 128 + n]);
}

// ---------------------------------------------------------------------------
// Bucket histogram: bcnt[b] = #edges with dst>>BSHIFT == b (LDS-aggregated)
// ---------------------------------------------------------------------------
__global__ __launch_bounds__(256) void bhist_kernel(const int* __restrict__ dst,
                                                    int* __restrict__ bcnt,
                                                    int E, int B) {
    __shared__ int h[BMAX];
    for (int i = threadIdx.x; i < B; i += 256) h[i] = 0;
    __syncthreads();
    const int stride = gridDim.x * blockDim.x;
    for (int e = blockIdx.x * blockDim.x + threadIdx.x; e < E; e += stride)
        atomicAdd(&h[dst[e] >> BSHIFT], 1);
    __syncthreads();
    for (int i = threadIdx.x; i < B; i += 256)
        if (h[i]) atomicAdd(&bcnt[i], h[i]);
}

// Exclusive scan over buckets; bcursor is consumed by bscatter, bstart persists.
__global__ __launch_bounds__(512) void bscan_kernel(const int* __restrict__ bcnt,
                                                    int* __restrict__ bcursor,
                                                    int* __restrict__ bstart, int B) {
    __shared__ int sh[512];
    const int t = threadIdx.x;
    int v = (t < B) ? bcnt[t] : 0;
    sh[t] = v;
    __syncthreads();
    for (int d = 1; d < 512; d <<= 1) {
        int u = (t >= d) ? sh[t - d] : 0;
        __syncthreads();
        sh[t] += u;
        __syncthreads();
    }
    if (t < B) {
        int excl = sh[t] - v;
        bcursor[t] = excl;
        bstart[t] = excl;
    }
    if (t == B - 1) bstart[B] = sh[t];
}

// Partition edges into dst-buckets. Packed: src (24 bits) | local-dst (8 bits).
__global__ __launch_bounds__(256) void bscatter_kernel(const int* __restrict__ src,
                                                       const int* __restrict__ dst,
                                                       int* __restrict__ bcursor,
                                                       unsigned* __restrict__ pairs,
                                                       int E, int B) {
    __shared__ int h[BMAX];
    __shared__ int base[BMAX];
    const int t = threadIdx.x;
    for (int i = t; i < B; i += 256) h[i] = 0;
    __syncthreads();
    const int chunk = (E + gridDim.x - 1) / gridDim.x;
    const int e0 = blockIdx.x * chunk;
    const int e1 = min(e0 + chunk, E);
    for (int e = e0 + t; e < e1; e += 256)
        atomicAdd(&h[dst[e] >> BSHIFT], 1);
    __syncthreads();
    for (int i = t; i < B; i += 256) {
        int c = h[i];
        base[i] = c ? atomicAdd(&bcursor[i], c) : 0;
    }
    __syncthreads();
    for (int i = t; i < B; i += 256) h[i] = base[i];
    __syncthreads();
    for (int e = e0 + t; e < e1; e += 256) {
        int d = dst[e];
        int pos = atomicAdd(&h[d >> BSHIFT], 1);
        pairs[pos] = (unsigned)src[e] | ((unsigned)(d & BMASK) << 24);
    }
}

// ---------------------------------------------------------------------------
// Per-bucket finalize: histogram 256 local dsts -> LDS scan -> node offsets +
// scatter src into csr. Replaces count2 + 3 scan kernels + fillB; all atomics
// in LDS, csr writes land in a contiguous per-bucket window.
// ---------------------------------------------------------------------------
__global__ __launch_bounds__(256) void bfinal_kernel(const unsigned* __restrict__ pairs,
                                                     const int* __restrict__ bstart,
                                                     int* __restrict__ offsets,
                                                     int* __restrict__ csr,
                                                     int N, int E) {
    __shared__ int h[256];
    __shared__ int cur[256];
    const int b = blockIdx.x;
    const int t = threadIdx.x;
    const int e0 = bstart[b], e1 = bstart[b + 1];
    h[t] = 0;
    __syncthreads();
    for (int e = e0 + t; e < e1; e += 256)
        atomicAdd(&h[pairs[e] >> 24], 1);
    __syncthreads();
    int v = h[t];
    for (int d = 1; d < 256; d <<= 1) {
        int u = (t >= d) ? h[t - d] : 0;
        __syncthreads();
        h[t] += u;
        __syncthreads();
    }
    const int base = e0 + (h[t] - v);   // exclusive prefix within bucket
    const int node = (b << BSHIFT) + t;
    if (node < N) offsets[node] = base;
    if (b == (int)gridDim.x - 1 && t == 255) offsets[N] = E;
    cur[t] = base;
    __syncthreads();
    for (int e = e0 + t; e < e1; e += 256) {
        unsigned pr = pairs[e];
        int pos = atomicAdd(&cur[pr >> 24], 1);
        csr[pos] = (int)(pr & 0xFFFFFFu);
    }
}

// ---------------------------------------------------------------------------
// Hb[n][:] = bf16( (xb[n][:] + sum_neighbors xb[s][:]) / (deg+1) )
// One wave per node; 4 lane-groups of 16, each group gathers one neighbor row
// as uint4 (16B/lane, 1 KB per load instruction covers 4 neighbors), 2-deep
// software pipeline (2 KB in flight / wave). 32-bit byte offsets keep address
// math to 1 VALU op. Cross-group combine via shfl_xor at the end.
// ---------------------------------------------------------------------------
static __device__ inline void acc8(float* a, uint4 u) {
    a[0] += b2f_lo(u.x); a[1] += b2f_hi(u.x);
    a[2] += b2f_lo(u.y); a[3] += b2f_hi(u.y);
    a[4] += b2f_lo(u.z); a[5] += b2f_hi(u.z);
    a[6] += b2f_lo(u.w); a[7] += b2f_hi(u.w);
}

__global__ __launch_bounds__(256) void aggregate_kernel(const unsigned short* __restrict__ xb,
                                                        const int* __restrict__ offsets,
                                                        const int* __restrict__ csr,
                                                        unsigned short* __restrict__ Hb,
                                                        int N) {
    const int node = (blockIdx.x * blockDim.x + threadIdx.x) >> 6;
    if (node >= N) return;
    const int lane = threadIdx.x & 63;
    const int g = lane >> 4;              // neighbor slot 0..3
    const unsigned poff = (unsigned)((lane & 15) << 4);  // 16B chunk in row
    const int start = offsets[node];
    const int end   = offsets[node + 1];
    const int deg   = end - start;
    const char* __restrict__ xc = (const char*)xb;

    float a[8];
#pragma unroll
    for (int i = 0; i < 8; ++i) a[i] = 0.f;

    const int jlim = start + (deg & ~3);  // full rounds of 4 neighbors
    int j = start + g;
    for (; j + 4 < jlim; j += 8) {        // 8 neighbors (2 KB) in flight
        int s0 = csr[j];
        int s1 = csr[j + 4];
        uint4 u0 = *(const uint4*)(xc + (((unsigned)s0 << 8) | poff));
        uint4 u1 = *(const uint4*)(xc + (((unsigned)s1 << 8) | poff));
        acc8(a, u0);
        acc8(a, u1);
    }
    if (j < jlim) {
        int s0 = csr[j];
        uint4 u0 = *(const uint4*)(xc + (((unsigned)s0 << 8) | poff));
        acc8(a, u0);
    }
    if (g < (deg & 3)) {                  // tail neighbors
        int s0 = csr[jlim + g];
        uint4 u0 = *(const uint4*)(xc + (((unsigned)s0 << 8) | poff));
        acc8(a, u0);
    }

    // combine the 4 lane-groups: lane ends with sum over {l, l^16, l^32, l^48}
#pragma unroll
    for (int i = 0; i < 8; ++i) {
        a[i] += __shfl_xor(a[i], 16);
        a[i] += __shfl_xor(a[i], 32);
    }

    // self term (added once, post-reduce; duplicated across groups consistently)
    uint4 us = *(const uint4*)(xc + (((unsigned)node << 8) | poff));
    acc8(a, us);

    const float inv = 1.0f / (float)(deg + 1);
    if (g == 0) {
        uint4 o;
        o.x = (unsigned)f2b(a[0] * inv) | ((unsigned)f2b(a[1] * inv) << 16);
        o.y = (unsigned)f2b(a[2] * inv) | ((unsigned)f2b(a[3] * inv) << 16);
        o.z = (unsigned)f2b(a[4] * inv) | ((unsigned)f2b(a[5] * inv) << 16);
        o.w = (unsigned)f2b(a[6] * inv) | ((unsigned)f2b(a[7] * inv) << 16);
        *(uint4*)((char*)Hb + (((unsigned)node << 8) | poff)) = o;
    }
}

// ---------------------------------------------------------------------------
// MFMA GEMM: out[r][c] = leaky( sum_k H[r][k] * W[k][c] + b[c] )
// 128 rows x 128 cols per block, 256 threads = 4 waves; wave w covers rows
// w*32..w*32+31 as 2 row-tiles x 8 col-tiles of 16x16x32 bf16 MFMA.
// LDS: Ha[128 rows][16 chunks], Wa[128 n][16 chunks], chunk=16B, XOR-swizzled
// (phys chunk = c ^ (row&15)) -> all b128 reads/writes are 2-way = conflict-free.
// A-frag: A[m=lane&15][k=quad*8+j]; B-frag: B[k=quad*8+j][n=lane&15] via Wt[n][k];
// C/D: col=lane&15, row=quad*4+reg (HW-verified layouts).
// ---------------------------------------------------------------------------
template <bool OUT_BF16>
__global__ __launch_bounds__(256) void gemm_mfma(const unsigned short* __restrict__ Hb,
                                                 const unsigned short* __restrict__ Wt,
                                                 const float* __restrict__ b,
                                                 void* __restrict__ outv, int N) {
    __shared__ unsigned short Ha[128 * 128];  // 32 KB
    __shared__ unsigned short Wa[128 * 128];  // 32 KB
    const int tid = threadIdx.x;
    const int row0 = blockIdx.x * 128;

    // Stage Ha (2048 16B chunks) — global reads coalesced, LDS writes swizzled
#pragma unroll
    for (int it = 0; it < 8; ++it) {
        int idx = it * 256 + tid;
        int r = idx >> 4, c = idx & 15;
        int gr = row0 + r;
        uint4 v = make_uint4(0, 0, 0, 0);
        if (gr < N) v = *(const uint4*)(Hb + (long long)gr * 128 + c * 8);
        *(uint4*)(Ha + r * 128 + ((c ^ (r & 15)) << 3)) = v;
    }
    // Stage Wa (Wt is [n][k] bf16, 2048 chunks)
#pragma unroll
    for (int it = 0; it < 8; ++it) {
        int idx = it * 256 + tid;
        int r = idx >> 4, c = idx & 15;
        uint4 v = *(const uint4*)(Wt + r * 128 + c * 8);
        *(uint4*)(Wa + r * 128 + ((c ^ (r & 15)) << 3)) = v;
    }
    __syncthreads();

    const int w = tid >> 6;
    const int lane = tid & 63;
    const int m = lane & 15;   // A row-in-tile / B col-in-tile / C col
    const int q = lane >> 4;   // quad

    f32x4 acc[2][8];
#pragma unroll
    for (int rt = 0; rt < 2; ++rt)
#pragma unroll
        for (int ct = 0; ct < 8; ++ct) acc[rt][ct] = (f32x4){0.f, 0.f, 0.f, 0.f};

#pragma unroll
    for (int kk = 0; kk < 4; ++kk) {
        const int chunk = kk * 4 + q;  // this lane's 16B chunk (8 bf16 of k)
        bf16x8 af[2];
#pragma unroll
        for (int rt = 0; rt < 2; ++rt) {
            int r = w * 32 + rt * 16 + m;
            af[rt] = *(const bf16x8*)(Ha + r * 128 + ((chunk ^ (r & 15)) << 3));
        }
#pragma unroll
        for (int ct = 0; ct < 8; ++ct) {
            int n = ct * 16 + m;
            bf16x8 bfr = *(const bf16x8*)(Wa + n * 128 + ((chunk ^ (n & 15)) << 3));
            acc[0][ct] = __builtin_amdgcn_mfma_f32_16x16x32_bf16(af[0], bfr, acc[0][ct], 0, 0, 0);
            acc[1][ct] = __builtin_amdgcn_mfma_f32_16x16x32_bf16(af[1], bfr, acc[1][ct], 0, 0, 0);
        }
    }

    // Epilogue: bias + leaky-relu, store (fp32 or bf16)
#pragma unroll
    for (int ct = 0; ct < 8; ++ct) {
        const float bias = b[ct * 16 + m];
        const int gcol = ct * 16 + m;
#pragma unroll
        for (int rt = 0; rt < 2; ++rt) {
#pragma unroll
            for (int reg = 0; reg < 4; ++reg) {
                int grow = row0 + w * 32 + rt * 16 + q * 4 + reg;
                if (grow < N) {
                    float v = acc[rt][ct][reg] + bias;
                    v = v > 0.f ? v : v * NEG_SLOPE;
                    if (OUT_BF16)
                        ((unsigned short*)outv)[(long long)grow * 128 + gcol] = f2b(v);
                    else
                        ((float*)outv)[(long long)grow * 128 + gcol] = v;
                }
            }
        }
    }
}

extern "C" void kernel_launch(void* const* d_in, const int* in_sizes, int n_in,
                              void* d_out, int out_size, void* d_ws, size_t ws_size,
                              hipStream_t stream) {
    const float* feat = (const float*)d_in[0];
    const int*   edges = (const int*)d_in[1];
    const float* W1 = (const float*)d_in[2];
    const float* b1 = (const float*)d_in[3];
    const float* W2 = (const float*)d_in[4];
    const float* b2 = (const float*)d_in[5];
    float* out = (float*)d_out;

    const int N = in_sizes[0] / 128;
    const int E = in_sizes[1] / 2;
    const int* src = edges;
    const int* dst = edges + E;
    const int B = (N + (1 << BSHIFT) - 1) >> BSHIFT;

    // Workspace layout (all 16B-aligned):
    //   featb:  N*128 bf16 (25.6 MB) — feat bf16; REUSED as h1b after aggregate-1
    //   Hb:     N*128 bf16 (25.6 MB) — aggregated features; pairs (E uint) aliased
    //   Wt1,Wt2: 128*128 bf16 each
    //   offsets/bcnt/bcursor/bstart/csr: ints
    unsigned short* featb = (unsigned short*)d_ws;
    unsigned short* Hb    = featb + (size_t)N * 128;
    unsigned*       pairs = (unsigned*)Hb;          // dead before aggregate-1
    unsigned short* Wt1   = Hb + (size_t)N * 128;
    unsigned short* Wt2   = Wt1 + 128 * 128;
    int* offsets = (int*)(Wt2 + 128 * 128);
    int* bcnt    = offsets + (N + 1);
    int* bcursor = bcnt + B;
    int* bstart  = bcursor + B;
    int* csr     = bstart + (B + 1);

    // ---- dtype conversions (independent of CSR build) ----
    long long nfeat = (long long)N * 128;
    cvt_feat<<<(int)((nfeat / 4 + 255) / 256), 256, 0, stream>>>(feat, featb, nfeat);
    cvt_w<<<64, 256, 0, stream>>>(W1, W2, Wt1, Wt2);

    // ---- Build CSR (dst -> list of src) via bucket radix ----
    hipMemsetAsync(bcnt, 0, (size_t)B * sizeof(int), stream);
    bhist_kernel<<<256, 256, 0, stream>>>(dst, bcnt, E, B);
    bscan_kernel<<<1, 512, 0, stream>>>(bcnt, bcursor, bstart, B);
    bscatter_kernel<<<256, 256, 0, stream>>>(src, dst, bcursor, pairs, E, B);
    bfinal_kernel<<<B, 256, 0, stream>>>(pairs, bstart, offsets, csr, N, E);

    const int aggGrid = (N + 3) / 4;
    const int gemmGrid = (N + 127) / 128;

    // ---- Layer 1: aggregate bf16 -> Hb; GEMM writes h1 bf16 into featb ----
    aggregate_kernel<<<aggGrid, 256, 0, stream>>>(featb, offsets, csr, Hb, N);
    gemm_mfma<true><<<gemmGrid, 256, 0, stream>>>(Hb, Wt1, b1, (void*)featb, N);

    // ---- Layer 2: aggregate h1b -> Hb; GEMM writes fp32 to d_out ----
    aggregate_kernel<<<aggGrid, 256, 0, stream>>>(featb, offsets, csr, Hb, N);
    gemm_mfma<false><<<gemmGrid, 256, 0, stream>>>(Hb, Wt2, b2, (void*)out, N);
}

// Round 2
// 365.078 us; speedup vs baseline: 1.2078x; 1.0139x over previous
//
#include <hip/hip_runtime.h>

#define NEG_SLOPE 0.01f
#define BSHIFT 8          // nodes per dst-bucket = 256
#define BMASK 255
#define BMAX 512          // LDS histogram capacity (supports N <= 131072)

typedef __attribute__((ext_vector_type(8))) short bf16x8;
typedef __attribute__((ext_vector_type(4))) float f32x4;
typedef __attribute__((ext_vector_type(2))) float f32x2;

// fp32 -> bf16 (RNE, normals only — fine for this data)
static __device__ inline unsigned short f2b(float f) {
    unsigned u = __builtin_bit_cast(unsigned, f);
    return (unsigned short)((u + 0x7FFF + ((u >> 16) & 1)) >> 16);
}
static __device__ inline float b2f_lo(unsigned u) {
    return __builtin_bit_cast(float, u << 16);
}
static __device__ inline float b2f_hi(unsigned u) {
    return __builtin_bit_cast(float, u & 0xFFFF0000u);
}

// ---------------------------------------------------------------------------
// feat fp32 -> bf16 (N*128 elements, multiple of 4)
// ---------------------------------------------------------------------------
__global__ __launch_bounds__(256) void cvt_feat(const float* __restrict__ x,
                                                unsigned short* __restrict__ xb,
                                                long long n) {
    long long i = ((long long)blockIdx.x * 256 + threadIdx.x) * 4;
    if (i < n) {
        float4 v = *(const float4*)(x + i);
        ushort4 o;
        o.x = f2b(v.x); o.y = f2b(v.y); o.z = f2b(v.z); o.w = f2b(v.w);
        *(ushort4*)(xb + i) = o;
    }
}

// ---------------------------------------------------------------------------
// W[k][n] fp32 -> Wt[n][k] bf16, both layers (128x128 each; tiny one-time cost)
// ---------------------------------------------------------------------------
__global__ __launch_bounds__(256) void cvt_w(const float* __restrict__ W1,
                                             const float* __restrict__ W2,
                                             unsigned short* __restrict__ Wt1,
                                             unsigned short* __restrict__ Wt2) {
    int i = blockIdx.x * 256 + threadIdx.x;   // 0..16383
    int n = i & 127, k = i >> 7;
    Wt1[n * 128 + k] = f2b(W1[k * 128 + n]);
    Wt2[n * 128 + k] = f2b(W2[k * 128 + n]);
}

// ---------------------------------------------------------------------------
// Bucket histogram: bcnt[b] = #edges with dst>>BSHIFT == b (LDS-aggregated)
// ---------------------------------------------------------------------------
__global__ __launch_bounds__(256) void bhist_kernel(const int* __restrict__ dst,
                                                    int* __restrict__ bcnt,
                                                    int E, int B) {
    __shared__ int h[BMAX];
    for (int i = threadIdx.x; i < B; i += 256) h[i] = 0;
    __syncthreads();
    const int stride = gridDim.x * blockDim.x;
    for (int e = blockIdx.x * blockDim.x + threadIdx.x; e < E; e += stride)
        atomicAdd(&h[dst[e] >> BSHIFT], 1);
    __syncthreads();
    for (int i = threadIdx.x; i < B; i += 256)
        if (h[i]) atomicAdd(&bcnt[i], h[i]);
}

// Exclusive scan over buckets; bcursor is consumed by bscatter, bstart persists.
__global__ __launch_bounds__(512) void bscan_kernel(const int* __restrict__ bcnt,
                                                    int* __restrict__ bcursor,
                                                    int* __restrict__ bstart, int B) {
    __shared__ int sh[512];
    const int t = threadIdx.x;
    int v = (t < B) ? bcnt[t] : 0;
    sh[t] = v;
    __syncthreads();
    for (int d = 1; d < 512; d <<= 1) {
        int u = (t >= d) ? sh[t - d] : 0;
        __syncthreads();
        sh[t] += u;
        __syncthreads();
    }
    if (t < B) {
        int excl = sh[t] - v;
        bcursor[t] = excl;
        bstart[t] = excl;
    }
    if (t == B - 1) bstart[B] = sh[t];
}

// Partition edges into dst-buckets. Packed: src (24 bits) | local-dst (8 bits).
__global__ __launch_bounds__(256) void bscatter_kernel(const int* __restrict__ src,
                                                       const int* __restrict__ dst,
                                                       int* __restrict__ bcursor,
                                                       unsigned* __restrict__ pairs,
                                                       int E, int B) {
    __shared__ int h[BMAX];
    __shared__ int base[BMAX];
    const int t = threadIdx.x;
    for (int i = t; i < B; i += 256) h[i] = 0;
    __syncthreads();
    const int chunk = (E + gridDim.x - 1) / gridDim.x;
    const int e0 = blockIdx.x * chunk;
    const int e1 = min(e0 + chunk, E);
    for (int e = e0 + t; e < e1; e += 256)
        atomicAdd(&h[dst[e] >> BSHIFT], 1);
    __syncthreads();
    for (int i = t; i < B; i += 256) {
        int c = h[i];
        base[i] = c ? atomicAdd(&bcursor[i], c) : 0;
    }
    __syncthreads();
    for (int i = t; i < B; i += 256) h[i] = base[i];
    __syncthreads();
    for (int e = e0 + t; e < e1; e += 256) {
        int d = dst[e];
        int pos = atomicAdd(&h[d >> BSHIFT], 1);
        pairs[pos] = (unsigned)src[e] | ((unsigned)(d & BMASK) << 24);
    }
}

// ---------------------------------------------------------------------------
// Per-bucket finalize: histogram 256 local dsts -> LDS scan -> node offsets +
// scatter src into csr. All atomics in LDS; csr writes land in a contiguous
// per-bucket window.
// ---------------------------------------------------------------------------
__global__ __launch_bounds__(256) void bfinal_kernel(const unsigned* __restrict__ pairs,
                                                     const int* __restrict__ bstart,
                                                     int* __restrict__ offsets,
                                                     int* __restrict__ csr,
                                                     int N, int E) {
    __shared__ int h[256];
    __shared__ int cur[256];
    const int b = blockIdx.x;
    const int t = threadIdx.x;
    const int e0 = bstart[b], e1 = bstart[b + 1];
    h[t] = 0;
    __syncthreads();
    for (int e = e0 + t; e < e1; e += 256)
        atomicAdd(&h[pairs[e] >> 24], 1);
    __syncthreads();
    int v = h[t];
    for (int d = 1; d < 256; d <<= 1) {
        int u = (t >= d) ? h[t - d] : 0;
        __syncthreads();
        h[t] += u;
        __syncthreads();
    }
    const int base = e0 + (h[t] - v);   // exclusive prefix within bucket
    const int node = (b << BSHIFT) + t;
    if (node < N) offsets[node] = base;
    if (b == (int)gridDim.x - 1 && t == 255) offsets[N] = E;
    cur[t] = base;
    __syncthreads();
    for (int e = e0 + t; e < e1; e += 256) {
        unsigned pr = pairs[e];
        int pos = atomicAdd(&cur[pr >> 24], 1);
        csr[pos] = (int)(pr & 0xFFFFFFu);
    }
}

// ---------------------------------------------------------------------------
// Hb[n][:] = bf16( (xb[n][:] + sum_neighbors xb[s][:]) / (deg+1) )
// One wave per node; 4 lane-groups of 16, each group gathers one neighbor row
// per round as uint4 (16B/lane, 1 KB per load instruction = 4 rows/wave).
// 4-deep software pipeline: 4 gathers (4 KB/wave) in flight, with csr indices
// for the NEXT 4 rounds prefetched before the accumulates of the current 4
// (breaks the csr->gather serial chain). Accumulators are f32x2 so the
// packed-FP32 path (v_pk_add_f32, gfx90a+) halves add instruction count.
// Cross-group combine via shfl_xor at the end.
// ---------------------------------------------------------------------------
static __device__ inline f32x2 up2(unsigned u) {
    return (f32x2){ b2f_lo(u), b2f_hi(u) };
}
static __device__ inline void accp(f32x2* A, uint4 u) {
    A[0] += up2(u.x);
    A[1] += up2(u.y);
    A[2] += up2(u.z);
    A[3] += up2(u.w);
}

__global__ __launch_bounds__(256) void aggregate_kernel(const unsigned short* __restrict__ xb,
                                                        const int* __restrict__ offsets,
                                                        const int* __restrict__ csr,
                                                        unsigned short* __restrict__ Hb,
                                                        int N) {
    const int node = (blockIdx.x * blockDim.x + threadIdx.x) >> 6;
    if (node >= N) return;
    const int lane = threadIdx.x & 63;
    const int g = lane >> 4;              // neighbor slot 0..3
    const unsigned poff = (unsigned)((lane & 15) << 4);  // 16B chunk in row
    const int start = offsets[node];
    const int end   = offsets[node + 1];
    const int deg   = end - start;
    const char* __restrict__ xc = (const char*)xb;

    // self row: issue early, consume at the end
    const uint4 us = *(const uint4*)(xc + (((unsigned)node << 8) | poff));

    f32x2 A[4];
    A[0] = A[1] = A[2] = A[3] = (f32x2){0.f, 0.f};

    const int rounds = deg >> 2;          // rounds of 4 neighbors (one/group)
    const int base = start + g;
    int r = 0;
    if (rounds >= 4) {
        int i0 = csr[base], i1 = csr[base + 4], i2 = csr[base + 8], i3 = csr[base + 12];
        while (true) {
            uint4 u0 = *(const uint4*)(xc + (((unsigned)i0 << 8) | poff));
            uint4 u1 = *(const uint4*)(xc + (((unsigned)i1 << 8) | poff));
            uint4 u2 = *(const uint4*)(xc + (((unsigned)i2 << 8) | poff));
            uint4 u3 = *(const uint4*)(xc + (((unsigned)i3 << 8) | poff));
            r += 4;
            const bool more = (r + 4 <= rounds);   // wave-uniform
            if (more) {
                const int nb = base + 4 * r;       // nb+12 <= end-1, in-bounds
                i0 = csr[nb]; i1 = csr[nb + 4]; i2 = csr[nb + 8]; i3 = csr[nb + 12];
            }
            accp(A, u0); accp(A, u1); accp(A, u2); accp(A, u3);
            if (!more) break;
        }
    }
    for (; r < rounds; ++r) {
        int s = csr[base + 4 * r];
        uint4 u = *(const uint4*)(xc + (((unsigned)s << 8) | poff));
        accp(A, u);
    }
    if (g < (deg & 3)) {                  // tail neighbors
        int s = csr[start + (rounds << 2) + g];
        uint4 u = *(const uint4*)(xc + (((unsigned)s << 8) | poff));
        accp(A, u);
    }

    // combine the 4 lane-groups: lane ends with sum over {l, l^16, l^32, l^48}
    float a[8];
    a[0] = A[0].x; a[1] = A[0].y; a[2] = A[1].x; a[3] = A[1].y;
    a[4] = A[2].x; a[5] = A[2].y; a[6] = A[3].x; a[7] = A[3].y;
#pragma unroll
    for (int i = 0; i < 8; ++i) {
        a[i] += __shfl_xor(a[i], 16);
        a[i] += __shfl_xor(a[i], 32);
    }

    // self term (added once, post-reduce; duplicated across groups consistently)
    a[0] += b2f_lo(us.x); a[1] += b2f_hi(us.x);
    a[2] += b2f_lo(us.y); a[3] += b2f_hi(us.y);
    a[4] += b2f_lo(us.z); a[5] += b2f_hi(us.z);
    a[6] += b2f_lo(us.w); a[7] += b2f_hi(us.w);

    const float inv = 1.0f / (float)(deg + 1);
    if (g == 0) {
        uint4 o;
        o.x = (unsigned)f2b(a[0] * inv) | ((unsigned)f2b(a[1] * inv) << 16);
        o.y = (unsigned)f2b(a[2] * inv) | ((unsigned)f2b(a[3] * inv) << 16);
        o.z = (unsigned)f2b(a[4] * inv) | ((unsigned)f2b(a[5] * inv) << 16);
        o.w = (unsigned)f2b(a[6] * inv) | ((unsigned)f2b(a[7] * inv) << 16);
        *(uint4*)((char*)Hb + (((unsigned)node << 8) | poff)) = o;
    }
}

// ---------------------------------------------------------------------------
// MFMA GEMM: out[r][c] = leaky( sum_k H[r][k] * W[k][c] + b[c] )
// 128 rows x 128 cols per block, 256 threads = 4 waves; wave w covers rows
// w*32..w*32+31 as 2 row-tiles x 8 col-tiles of 16x16x32 bf16 MFMA.
// LDS: Ha[128 rows][16 chunks], Wa[128 n][16 chunks], chunk=16B, XOR-swizzled
// (phys chunk = c ^ (row&15)) -> all b128 reads/writes are 2-way = conflict-free.
// A-frag: A[m=lane&15][k=quad*8+j]; B-frag: B[k=quad*8+j][n=lane&15] via Wt[n][k];
// C/D: col=lane&15, row=quad*4+reg (HW-verified layouts).
// ---------------------------------------------------------------------------
template <bool OUT_BF16>
__global__ __launch_bounds__(256) void gemm_mfma(const unsigned short* __restrict__ Hb,
                                                 const unsigned short* __restrict__ Wt,
                                                 const float* __restrict__ b,
                                                 void* __restrict__ outv, int N) {
    __shared__ unsigned short Ha[128 * 128];  // 32 KB
    __shared__ unsigned short Wa[128 * 128];  // 32 KB
    const int tid = threadIdx.x;
    const int row0 = blockIdx.x * 128;

    // Stage Ha (2048 16B chunks) — global reads coalesced, LDS writes swizzled
#pragma unroll
    for (int it = 0; it < 8; ++it) {
        int idx = it * 256 + tid;
        int r = idx >> 4, c = idx & 15;
        int gr = row0 + r;
        uint4 v = make_uint4(0, 0, 0, 0);
        if (gr < N) v = *(const uint4*)(Hb + (long long)gr * 128 + c * 8);
        *(uint4*)(Ha + r * 128 + ((c ^ (r & 15)) << 3)) = v;
    }
    // Stage Wa (Wt is [n][k] bf16, 2048 chunks)
#pragma unroll
    for (int it = 0; it < 8; ++it) {
        int idx = it * 256 + tid;
        int r = idx >> 4, c = idx & 15;
        uint4 v = *(const uint4*)(Wt + r * 128 + c * 8);
        *(uint4*)(Wa + r * 128 + ((c ^ (r & 15)) << 3)) = v;
    }
    __syncthreads();

    const int w = tid >> 6;
    const int lane = tid & 63;
    const int m = lane & 15;   // A row-in-tile / B col-in-tile / C col
    const int q = lane >> 4;   // quad

    f32x4 acc[2][8];
#pragma unroll
    for (int rt = 0; rt < 2; ++rt)
#pragma unroll
        for (int ct = 0; ct < 8; ++ct) acc[rt][ct] = (f32x4){0.f, 0.f, 0.f, 0.f};

#pragma unroll
    for (int kk = 0; kk < 4; ++kk) {
        const int chunk = kk * 4 + q;  // this lane's 16B chunk (8 bf16 of k)
        bf16x8 af[2];
#pragma unroll
        for (int rt = 0; rt < 2; ++rt) {
            int r = w * 32 + rt * 16 + m;
            af[rt] = *(const bf16x8*)(Ha + r * 128 + ((chunk ^ (r & 15)) << 3));
        }
#pragma unroll
        for (int ct = 0; ct < 8; ++ct) {
            int n = ct * 16 + m;
            bf16x8 bfr = *(const bf16x8*)(Wa + n * 128 + ((chunk ^ (n & 15)) << 3));
            acc[0][ct] = __builtin_amdgcn_mfma_f32_16x16x32_bf16(af[0], bfr, acc[0][ct], 0, 0, 0);
            acc[1][ct] = __builtin_amdgcn_mfma_f32_16x16x32_bf16(af[1], bfr, acc[1][ct], 0, 0, 0);
        }
    }

    // Epilogue: bias + leaky-relu, store (fp32 or bf16)
#pragma unroll
    for (int ct = 0; ct < 8; ++ct) {
        const float bias = b[ct * 16 + m];
        const int gcol = ct * 16 + m;
#pragma unroll
        for (int rt = 0; rt < 2; ++rt) {
#pragma unroll
            for (int reg = 0; reg < 4; ++reg) {
                int grow = row0 + w * 32 + rt * 16 + q * 4 + reg;
                if (grow < N) {
                    float v = acc[rt][ct][reg] + bias;
                    v = v > 0.f ? v : v * NEG_SLOPE;
                    if (OUT_BF16)
                        ((unsigned short*)outv)[(long long)grow * 128 + gcol] = f2b(v);
                    else
                        ((float*)outv)[(long long)grow * 128 + gcol] = v;
                }
            }
        }
    }
}

extern "C" void kernel_launch(void* const* d_in, const int* in_sizes, int n_in,
                              void* d_out, int out_size, void* d_ws, size_t ws_size,
                              hipStream_t stream) {
    const float* feat = (const float*)d_in[0];
    const int*   edges = (const int*)d_in[1];
    const float* W1 = (const float*)d_in[2];
    const float* b1 = (const float*)d_in[3];
    const float* W2 = (const float*)d_in[4];
    const float* b2 = (const float*)d_in[5];
    float* out = (float*)d_out;

    const int N = in_sizes[0] / 128;
    const int E = in_sizes[1] / 2;
    const int* src = edges;
    const int* dst = edges + E;
    const int B = (N + (1 << BSHIFT) - 1) >> BSHIFT;

    // Workspace layout (all 16B-aligned):
    //   featb:  N*128 bf16 (25.6 MB) — feat bf16; REUSED as h1b after aggregate-1
    //   Hb:     N*128 bf16 (25.6 MB) — aggregated features; pairs (E uint) aliased
    //   Wt1,Wt2: 128*128 bf16 each
    //   offsets/bcnt/bcursor/bstart/csr: ints
    unsigned short* featb = (unsigned short*)d_ws;
    unsigned short* Hb    = featb + (size_t)N * 128;
    unsigned*       pairs = (unsigned*)Hb;          // dead before aggregate-1
    unsigned short* Wt1   = Hb + (size_t)N * 128;
    unsigned short* Wt2   = Wt1 + 128 * 128;
    int* offsets = (int*)(Wt2 + 128 * 128);
    int* bcnt    = offsets + (N + 1);
    int* bcursor = bcnt + B;
    int* bstart  = bcursor + B;
    int* csr     = bstart + (B + 1);

    // ---- dtype conversions (independent of CSR build) ----
    long long nfeat = (long long)N * 128;
    cvt_feat<<<(int)((nfeat / 4 + 255) / 256), 256, 0, stream>>>(feat, featb, nfeat);
    cvt_w<<<64, 256, 0, stream>>>(W1, W2, Wt1, Wt2);

    // ---- Build CSR (dst -> list of src) via bucket radix ----
    hipMemsetAsync(bcnt, 0, (size_t)B * sizeof(int), stream);
    bhist_kernel<<<256, 256, 0, stream>>>(dst, bcnt, E, B);
    bscan_kernel<<<1, 512, 0, stream>>>(bcnt, bcursor, bstart, B);
    bscatter_kernel<<<256, 256, 0, stream>>>(src, dst, bcursor, pairs, E, B);
    bfinal_kernel<<<B, 256, 0, stream>>>(pairs, bstart, offsets, csr, N, E);

    const int aggGrid = (N + 3) / 4;
    const int gemmGrid = (N + 127) / 128;

    // ---- Layer 1: aggregate bf16 -> Hb; GEMM writes h1 bf16 into featb ----
    aggregate_kernel<<<aggGrid, 256, 0, stream>>>(featb, offsets, csr, Hb, N);
    gemm_mfma<true><<<gemmGrid, 256, 0, stream>>>(Hb, Wt1, b1, (void*)featb, N);

    // ---- Layer 2: aggregate h1b -> Hb; GEMM writes fp32 to d_out ----
    aggregate_kernel<<<aggGrid, 256, 0, stream>>>(featb, offsets, csr, Hb, N);
    gemm_mfma<false><<<gemmGrid, 256, 0, stream>>>(Hb, Wt2, b2, (void*)out, N);
}

// Round 3
// 354.206 us; speedup vs baseline: 1.2449x; 1.0307x over previous
//
#include <hip/hip_runtime.h>

#define NEG_SLOPE 0.01f
#define BSHIFT 8          // nodes per dst-bucket = 256
#define BMASK 255
#define BMAX 512          // LDS histogram capacity (supports N <= 131072)
#define NPB 64            // nodes per aggregate block
#define CAP 4096          // staged csr entries per aggregate block (16 KB)

typedef __attribute__((ext_vector_type(8))) short bf16x8;
typedef __attribute__((ext_vector_type(4))) float f32x4;
typedef __attribute__((ext_vector_type(2))) float f32x2;

// fp32 -> bf16 (RNE, normals only — fine for this data)
static __device__ inline unsigned short f2b(float f) {
    unsigned u = __builtin_bit_cast(unsigned, f);
    return (unsigned short)((u + 0x7FFF + ((u >> 16) & 1)) >> 16);
}
static __device__ inline float b2f_lo(unsigned u) {
    return __builtin_bit_cast(float, u << 16);
}
static __device__ inline float b2f_hi(unsigned u) {
    return __builtin_bit_cast(float, u & 0xFFFF0000u);
}

// ---------------------------------------------------------------------------
// feat fp32 -> bf16 (N*128 elements, multiple of 4)
// ---------------------------------------------------------------------------
__global__ __launch_bounds__(256) void cvt_feat(const float* __restrict__ x,
                                                unsigned short* __restrict__ xb,
                                                long long n) {
    long long i = ((long long)blockIdx.x * 256 + threadIdx.x) * 4;
    if (i < n) {
        float4 v = *(const float4*)(x + i);
        ushort4 o;
        o.x = f2b(v.x); o.y = f2b(v.y); o.z = f2b(v.z); o.w = f2b(v.w);
        *(ushort4*)(xb + i) = o;
    }
}

// ---------------------------------------------------------------------------
// W[k][n] fp32 -> Wt[n][k] bf16, both layers; also zeroes bcnt (folds the
// memset dispatch away — runs before bhist on the same stream).
// ---------------------------------------------------------------------------
__global__ __launch_bounds__(256) void cvt_w(const float* __restrict__ W1,
                                             const float* __restrict__ W2,
                                             unsigned short* __restrict__ Wt1,
                                             unsigned short* __restrict__ Wt2,
                                             int* __restrict__ bcnt, int B) {
    int i = blockIdx.x * 256 + threadIdx.x;   // 0..16383
    if (i < B) bcnt[i] = 0;
    int n = i & 127, k = i >> 7;
    Wt1[n * 128 + k] = f2b(W1[k * 128 + n]);
    Wt2[n * 128 + k] = f2b(W2[k * 128 + n]);
}

// ---------------------------------------------------------------------------
// Bucket histogram: bcnt[b] = #edges with dst>>BSHIFT == b (LDS-aggregated)
// ---------------------------------------------------------------------------
__global__ __launch_bounds__(256) void bhist_kernel(const int* __restrict__ dst,
                                                    int* __restrict__ bcnt,
                                                    int E, int B) {
    __shared__ int h[BMAX];
    for (int i = threadIdx.x; i < B; i += 256) h[i] = 0;
    __syncthreads();
    const int stride = gridDim.x * blockDim.x;
    for (int e = blockIdx.x * blockDim.x + threadIdx.x; e < E; e += stride)
        atomicAdd(&h[dst[e] >> BSHIFT], 1);
    __syncthreads();
    for (int i = threadIdx.x; i < B; i += 256)
        if (h[i]) atomicAdd(&bcnt[i], h[i]);
}

// Exclusive scan over buckets; bcursor is consumed by bscatter, bstart persists.
__global__ __launch_bounds__(512) void bscan_kernel(const int* __restrict__ bcnt,
                                                    int* __restrict__ bcursor,
                                                    int* __restrict__ bstart, int B) {
    __shared__ int sh[512];
    const int t = threadIdx.x;
    int v = (t < B) ? bcnt[t] : 0;
    sh[t] = v;
    __syncthreads();
    for (int d = 1; d < 512; d <<= 1) {
        int u = (t >= d) ? sh[t - d] : 0;
        __syncthreads();
        sh[t] += u;
        __syncthreads();
    }
    if (t < B) {
        int excl = sh[t] - v;
        bcursor[t] = excl;
        bstart[t] = excl;
    }
    if (t == B - 1) bstart[B] = sh[t];
}

// Partition edges into dst-buckets. Packed: src (24 bits) | local-dst (8 bits).
__global__ __launch_bounds__(256) void bscatter_kernel(const int* __restrict__ src,
                                                       const int* __restrict__ dst,
                                                       int* __restrict__ bcursor,
                                                       unsigned* __restrict__ pairs,
                                                       int E, int B) {
    __shared__ int h[BMAX];
    __shared__ int base[BMAX];
    const int t = threadIdx.x;
    for (int i = t; i < B; i += 256) h[i] = 0;
    __syncthreads();
    const int chunk = (E + gridDim.x - 1) / gridDim.x;
    const int e0 = blockIdx.x * chunk;
    const int e1 = min(e0 + chunk, E);
    for (int e = e0 + t; e < e1; e += 256)
        atomicAdd(&h[dst[e] >> BSHIFT], 1);
    __syncthreads();
    for (int i = t; i < B; i += 256) {
        int c = h[i];
        base[i] = c ? atomicAdd(&bcursor[i], c) : 0;
    }
    __syncthreads();
    for (int i = t; i < B; i += 256) h[i] = base[i];
    __syncthreads();
    for (int e = e0 + t; e < e1; e += 256) {
        int d = dst[e];
        int pos = atomicAdd(&h[d >> BSHIFT], 1);
        pairs[pos] = (unsigned)src[e] | ((unsigned)(d & BMASK) << 24);
    }
}

// ---------------------------------------------------------------------------
// Per-bucket finalize: histogram 256 local dsts -> LDS scan -> node offsets +
// scatter src into csr. All atomics in LDS; csr writes land in a contiguous
// per-bucket window.
// ---------------------------------------------------------------------------
__global__ __launch_bounds__(256) void bfinal_kernel(const unsigned* __restrict__ pairs,
                                                     const int* __restrict__ bstart,
                                                     int* __restrict__ offsets,
                                                     int* __restrict__ csr,
                                                     int N, int E) {
    __shared__ int h[256];
    __shared__ int cur[256];
    const int b = blockIdx.x;
    const int t = threadIdx.x;
    const int e0 = bstart[b], e1 = bstart[b + 1];
    h[t] = 0;
    __syncthreads();
    for (int e = e0 + t; e < e1; e += 256)
        atomicAdd(&h[pairs[e] >> 24], 1);
    __syncthreads();
    int v = h[t];
    for (int d = 1; d < 256; d <<= 1) {
        int u = (t >= d) ? h[t - d] : 0;
        __syncthreads();
        h[t] += u;
        __syncthreads();
    }
    const int base = e0 + (h[t] - v);   // exclusive prefix within bucket
    const int node = (b << BSHIFT) + t;
    if (node < N) offsets[node] = base;
    if (b == (int)gridDim.x - 1 && t == 255) offsets[N] = E;
    cur[t] = base;
    __syncthreads();
    for (int e = e0 + t; e < e1; e += 256) {
        unsigned pr = pairs[e];
        int pos = atomicAdd(&cur[pr >> 24], 1);
        csr[pos] = (int)(pr & 0xFFFFFFu);
    }
}

// ---------------------------------------------------------------------------
// Aggregate: Hb[n][:] = bf16( (xb[n][:] + sum_neighbors xb[s][:]) / (deg+1) )
//
// Block = 64 consecutive nodes; their csr window is CONTIGUOUS (bucket sort),
// staged into LDS once -> index fetches never touch global latency.
// One wave per node at a time (4 waves x 16 nodes); 4 lane-groups of 16 each
// gather one full 256B row per gather instruction (4 rows / instr).
// All of a node's gathers (up to 8 rounds = 32 nbrs, + tail + self) are issued
// STRAIGHT-LINE before a sched_barrier(0) fence, so the compiler cannot
// re-serialize them to save registers: 6-10 loads (1.5-2.5 KB) stay in flight
// per wave. Accumulate in packed f32x2 (v_pk_add_f32).
// ---------------------------------------------------------------------------
static __device__ inline f32x2 up2(unsigned u) {
    return (f32x2){ b2f_lo(u), b2f_hi(u) };
}

#define GLOAD(s) (*(const uint4*)(xc + ((((unsigned)(s)) << 8) | poff)))
#define ACC4(u) do { A0 += up2((u).x); A1 += up2((u).y); \
                     A2 += up2((u).z); A3 += up2((u).w); } while (0)

static __device__ __forceinline__ void agg_node(const int* __restrict__ ip,
                                                int node, int deg,
                                                const char* __restrict__ xc,
                                                unsigned poff, int g,
                                                unsigned short* __restrict__ Hb) {
    const int rounds = deg >> 2;
    const int tailn  = deg & 3;
    f32x2 A0 = {0.f, 0.f}, A1 = {0.f, 0.f}, A2 = {0.f, 0.f}, A3 = {0.f, 0.f};
    uint4 b0, b1, b2, b3, c0, c1, c2, c3;

    // ---- issue phase: everything in flight before any consume ----
    const uint4 us = GLOAD(node);                       // self row
    if (rounds >= 1) b0 = GLOAD(ip[g]);
    if (rounds >= 2) b1 = GLOAD(ip[4 + g]);
    if (rounds >= 3) b2 = GLOAD(ip[8 + g]);
    if (rounds >= 4) b3 = GLOAD(ip[12 + g]);
    if (rounds >= 5) c0 = GLOAD(ip[16 + g]);
    if (rounds >= 6) c1 = GLOAD(ip[20 + g]);
    if (rounds >= 7) c2 = GLOAD(ip[24 + g]);
    if (rounds >= 8) c3 = GLOAD(ip[28 + g]);
    uint4 ut = make_uint4(0, 0, 0, 0);
    if (g < tailn) ut = GLOAD(ip[(rounds << 2) + g]);
    __builtin_amdgcn_sched_barrier(0);

    // ---- consume phase ----
    if (rounds >= 1) ACC4(b0);
    if (rounds >= 2) ACC4(b1);
    if (rounds >= 3) ACC4(b2);
    if (rounds >= 4) ACC4(b3);
    if (rounds >= 5) ACC4(c0);
    if (rounds >= 6) ACC4(c1);
    if (rounds >= 7) ACC4(c2);
    if (rounds >= 8) ACC4(c3);
    for (int r = 8; r < rounds; ++r) {                  // deg > 35: ~never
        uint4 u = GLOAD(ip[4 * r + g]);
        ACC4(u);
    }
    ACC4(ut);

    // combine the 4 lane-groups: butterfly leaves full sum in every lane
    float a[8];
    a[0] = A0.x; a[1] = A0.y; a[2] = A1.x; a[3] = A1.y;
    a[4] = A2.x; a[5] = A2.y; a[6] = A3.x; a[7] = A3.y;
#pragma unroll
    for (int i = 0; i < 8; ++i) {
        a[i] += __shfl_xor(a[i], 16);
        a[i] += __shfl_xor(a[i], 32);
    }
    // self term (post-reduce, added once)
    a[0] += b2f_lo(us.x); a[1] += b2f_hi(us.x);
    a[2] += b2f_lo(us.y); a[3] += b2f_hi(us.y);
    a[4] += b2f_lo(us.z); a[5] += b2f_hi(us.z);
    a[6] += b2f_lo(us.w); a[7] += b2f_hi(us.w);

    const float inv = 1.0f / (float)(deg + 1);
    if (g == 0) {
        uint4 o;
        o.x = (unsigned)f2b(a[0] * inv) | ((unsigned)f2b(a[1] * inv) << 16);
        o.y = (unsigned)f2b(a[2] * inv) | ((unsigned)f2b(a[3] * inv) << 16);
        o.z = (unsigned)f2b(a[4] * inv) | ((unsigned)f2b(a[5] * inv) << 16);
        o.w = (unsigned)f2b(a[6] * inv) | ((unsigned)f2b(a[7] * inv) << 16);
        *(uint4*)((char*)Hb + ((((unsigned)node) << 8) | poff)) = o;
    }
}

__global__ __launch_bounds__(256) void aggregate_kernel(const unsigned short* __restrict__ xb,
                                                        const int* __restrict__ offsets,
                                                        const int* __restrict__ csr,
                                                        unsigned short* __restrict__ Hb,
                                                        int N) {
    __shared__ int sIdx[CAP];
    __shared__ int sOff[NPB + 1];
    const int tid = threadIdx.x;
    const int node0 = blockIdx.x * NPB;
    const int nlocal = min(NPB, N - node0);
    if (tid <= nlocal) sOff[tid] = offsets[node0 + tid];
    __syncthreads();
    const int e0 = sOff[0];
    const int win = sOff[nlocal] - e0;
    for (int i = tid; i < win && i < CAP; i += 256) sIdx[i] = csr[e0 + i];
    __syncthreads();

    const int wv = tid >> 6;
    const int lane = tid & 63;
    const int g = lane >> 4;
    const unsigned poff = (unsigned)((lane & 15) << 4);
    const char* __restrict__ xc = (const char*)xb;

    for (int i = 0; i < 16; ++i) {
        const int ln = wv * 16 + i;
        if (ln >= nlocal) break;
        const int start = sOff[ln];
        const int deg = sOff[ln + 1] - start;
        const int node = node0 + ln;
        if (sOff[ln + 1] - e0 <= CAP) {
            agg_node(sIdx + (start - e0), node, deg, xc, poff, g, Hb);  // LDS indices
        } else {
            agg_node(csr + start, node, deg, xc, poff, g, Hb);          // rare fallback
        }
    }
}

// ---------------------------------------------------------------------------
// MFMA GEMM: out[r][c] = leaky( sum_k H[r][k] * W[k][c] + b[c] )
// 128 rows x 128 cols per block, 256 threads = 4 waves; wave w covers rows
// w*32..w*32+31 as 2 row-tiles x 8 col-tiles of 16x16x32 bf16 MFMA.
// W staged in LDS (reused by all 4 waves, XOR-swizzled, conflict-free b128);
// A-fragments stream STRAIGHT FROM GLOBAL (each wave reads 16 rows x 64 B
// aligned per kk — fully coalesced, data used once so LDS buys nothing).
// LDS 64->32 KB: blocks/CU 2->5.
// A-frag: A[m=lane&15][k=quad*8+j]; B-frag: B[k=quad*8+j][n=lane&15] via Wt[n][k];
// C/D: col=lane&15, row=quad*4+reg (HW-verified layouts).
// ---------------------------------------------------------------------------
template <bool OUT_BF16>
__global__ __launch_bounds__(256) void gemm_mfma(const unsigned short* __restrict__ Hb,
                                                 const unsigned short* __restrict__ Wt,
                                                 const float* __restrict__ b,
                                                 void* __restrict__ outv, int N) {
    __shared__ unsigned short Wa[128 * 128];  // 32 KB
    const int tid = threadIdx.x;
    const int row0 = blockIdx.x * 128;

    // Stage Wa (Wt is [n][k] bf16, 2048 16B chunks, swizzled)
#pragma unroll
    for (int it = 0; it < 8; ++it) {
        int idx = it * 256 + tid;
        int r = idx >> 4, c = idx & 15;
        uint4 v = *(const uint4*)(Wt + r * 128 + c * 8);
        *(uint4*)(Wa + r * 128 + ((c ^ (r & 15)) << 3)) = v;
    }
    __syncthreads();

    const int w = tid >> 6;
    const int lane = tid & 63;
    const int m = lane & 15;   // A row-in-tile / B col-in-tile / C col
    const int q = lane >> 4;   // quad

    // A rows for this lane (clamped; OOB rows never stored)
    const int r0 = row0 + w * 32 + m;
    const size_t ar0 = (size_t)min(r0, N - 1) * 128;
    const size_t ar1 = (size_t)min(r0 + 16, N - 1) * 128;

    f32x4 acc[2][8];
#pragma unroll
    for (int rt = 0; rt < 2; ++rt)
#pragma unroll
        for (int ct = 0; ct < 8; ++ct) acc[rt][ct] = (f32x4){0.f, 0.f, 0.f, 0.f};

#pragma unroll
    for (int kk = 0; kk < 4; ++kk) {
        const int chunk = kk * 4 + q;  // this lane's 16B chunk (8 bf16 of k)
        bf16x8 af0 = *(const bf16x8*)(Hb + ar0 + chunk * 8);
        bf16x8 af1 = *(const bf16x8*)(Hb + ar1 + chunk * 8);
#pragma unroll
        for (int ct = 0; ct < 8; ++ct) {
            int n = ct * 16 + m;
            bf16x8 bfr = *(const bf16x8*)(Wa + n * 128 + ((chunk ^ (n & 15)) << 3));
            acc[0][ct] = __builtin_amdgcn_mfma_f32_16x16x32_bf16(af0, bfr, acc[0][ct], 0, 0, 0);
            acc[1][ct] = __builtin_amdgcn_mfma_f32_16x16x32_bf16(af1, bfr, acc[1][ct], 0, 0, 0);
        }
    }

    // Epilogue: bias + leaky-relu, store (fp32 or bf16)
#pragma unroll
    for (int ct = 0; ct < 8; ++ct) {
        const float bias = b[ct * 16 + m];
        const int gcol = ct * 16 + m;
#pragma unroll
        for (int rt = 0; rt < 2; ++rt) {
#pragma unroll
            for (int reg = 0; reg < 4; ++reg) {
                int grow = row0 + w * 32 + rt * 16 + q * 4 + reg;
                if (grow < N) {
                    float v = acc[rt][ct][reg] + bias;
                    v = v > 0.f ? v : v * NEG_SLOPE;
                    if (OUT_BF16)
                        ((unsigned short*)outv)[(long long)grow * 128 + gcol] = f2b(v);
                    else
                        ((float*)outv)[(long long)grow * 128 + gcol] = v;
                }
            }
        }
    }
}

extern "C" void kernel_launch(void* const* d_in, const int* in_sizes, int n_in,
                              void* d_out, int out_size, void* d_ws, size_t ws_size,
                              hipStream_t stream) {
    const float* feat = (const float*)d_in[0];
    const int*   edges = (const int*)d_in[1];
    const float* W1 = (const float*)d_in[2];
    const float* b1 = (const float*)d_in[3];
    const float* W2 = (const float*)d_in[4];
    const float* b2 = (const float*)d_in[5];
    float* out = (float*)d_out;

    const int N = in_sizes[0] / 128;
    const int E = in_sizes[1] / 2;
    const int* src = edges;
    const int* dst = edges + E;
    const int B = (N + (1 << BSHIFT) - 1) >> BSHIFT;

    // Workspace layout (all 16B-aligned):
    //   featb:  N*128 bf16 (25.6 MB) — feat bf16; REUSED as h1b after aggregate-1
    //   Hb:     N*128 bf16 (25.6 MB) — aggregated features; pairs (E uint) aliased
    //   Wt1,Wt2: 128*128 bf16 each
    //   offsets/bcnt/bcursor/bstart/csr: ints
    unsigned short* featb = (unsigned short*)d_ws;
    unsigned short* Hb    = featb + (size_t)N * 128;
    unsigned*       pairs = (unsigned*)Hb;          // dead before aggregate-1
    unsigned short* Wt1   = Hb + (size_t)N * 128;
    unsigned short* Wt2   = Wt1 + 128 * 128;
    int* offsets = (int*)(Wt2 + 128 * 128);
    int* bcnt    = offsets + (N + 1);
    int* bcursor = bcnt + B;
    int* bstart  = bcursor + B;
    int* csr     = bstart + (B + 1);

    // ---- dtype conversions (independent of CSR build); cvt_w zeroes bcnt ----
    long long nfeat = (long long)N * 128;
    cvt_feat<<<(int)((nfeat / 4 + 255) / 256), 256, 0, stream>>>(feat, featb, nfeat);
    cvt_w<<<64, 256, 0, stream>>>(W1, W2, Wt1, Wt2, bcnt, B);

    // ---- Build CSR (dst -> list of src) via bucket radix ----
    bhist_kernel<<<256, 256, 0, stream>>>(dst, bcnt, E, B);
    bscan_kernel<<<1, 512, 0, stream>>>(bcnt, bcursor, bstart, B);
    bscatter_kernel<<<256, 256, 0, stream>>>(src, dst, bcursor, pairs, E, B);
    bfinal_kernel<<<B, 256, 0, stream>>>(pairs, bstart, offsets, csr, N, E);

    const int aggGrid = (N + NPB - 1) / NPB;
    const int gemmGrid = (N + 127) / 128;

    // ---- Layer 1: aggregate bf16 -> Hb; GEMM writes h1 bf16 into featb ----
    aggregate_kernel<<<aggGrid, 256, 0, stream>>>(featb, offsets, csr, Hb, N);
    gemm_mfma<true><<<gemmGrid, 256, 0, stream>>>(Hb, Wt1, b1, (void*)featb, N);

    // ---- Layer 2: aggregate h1b -> Hb; GEMM writes fp32 to d_out ----
    aggregate_kernel<<<aggGrid, 256, 0, stream>>>(featb, offsets, csr, Hb, N);
    gemm_mfma<false><<<gemmGrid, 256, 0, stream>>>(Hb, Wt2, b2, (void*)out, N);
}

// Round 4
// 344.062 us; speedup vs baseline: 1.2816x; 1.0295x over previous
//
#include <hip/hip_runtime.h>

#define NEG_SLOPE 0.01f
#define BSHIFT 8          // nodes per dst-bucket = 256
#define BMASK 255
#define BMAX 512          // LDS histogram capacity (supports N <= 131072)

typedef __attribute__((ext_vector_type(8))) short bf16x8;
typedef __attribute__((ext_vector_type(4))) float f32x4;
typedef __attribute__((ext_vector_type(2))) float f32x2;
typedef __attribute__((ext_vector_type(4))) unsigned u32x4;

// fp32 -> bf16 (RNE, normals only — fine for this data)
static __device__ inline unsigned short f2b(float f) {
    unsigned u = __builtin_bit_cast(unsigned, f);
    return (unsigned short)((u + 0x7FFF + ((u >> 16) & 1)) >> 16);
}
static __device__ inline float b2f_lo(unsigned u) {
    return __builtin_bit_cast(float, u << 16);
}
static __device__ inline float b2f_hi(unsigned u) {
    return __builtin_bit_cast(float, u & 0xFFFF0000u);
}

// ---------------------------------------------------------------------------
// feat fp32 -> bf16 (N*128 elements, multiple of 4)
// ---------------------------------------------------------------------------
__global__ __launch_bounds__(256) void cvt_feat(const float* __restrict__ x,
                                                unsigned short* __restrict__ xb,
                                                long long n) {
    long long i = ((long long)blockIdx.x * 256 + threadIdx.x) * 4;
    if (i < n) {
        float4 v = *(const float4*)(x + i);
        ushort4 o;
        o.x = f2b(v.x); o.y = f2b(v.y); o.z = f2b(v.z); o.w = f2b(v.w);
        *(ushort4*)(xb + i) = o;
    }
}

// ---------------------------------------------------------------------------
// W[k][n] fp32 -> Wt[n][k] bf16, both layers; also zeroes bcnt (folds the
// memset dispatch away — runs before bhist on the same stream).
// ---------------------------------------------------------------------------
__global__ __launch_bounds__(256) void cvt_w(const float* __restrict__ W1,
                                             const float* __restrict__ W2,
                                             unsigned short* __restrict__ Wt1,
                                             unsigned short* __restrict__ Wt2,
                                             int* __restrict__ bcnt, int B) {
    int i = blockIdx.x * 256 + threadIdx.x;   // 0..16383
    if (i < B) bcnt[i] = 0;
    int n = i & 127, k = i >> 7;
    Wt1[n * 128 + k] = f2b(W1[k * 128 + n]);
    Wt2[n * 128 + k] = f2b(W2[k * 128 + n]);
}

// ---------------------------------------------------------------------------
// Bucket histogram: bcnt[b] = #edges with dst>>BSHIFT == b (LDS-aggregated)
// ---------------------------------------------------------------------------
__global__ __launch_bounds__(256) void bhist_kernel(const int* __restrict__ dst,
                                                    int* __restrict__ bcnt,
                                                    int E, int B) {
    __shared__ int h[BMAX];
    for (int i = threadIdx.x; i < B; i += 256) h[i] = 0;
    __syncthreads();
    const int stride = gridDim.x * blockDim.x;
    for (int e = blockIdx.x * blockDim.x + threadIdx.x; e < E; e += stride)
        atomicAdd(&h[dst[e] >> BSHIFT], 1);
    __syncthreads();
    for (int i = threadIdx.x; i < B; i += 256)
        if (h[i]) atomicAdd(&bcnt[i], h[i]);
}

// Exclusive scan over buckets; bcursor is consumed by bscatter, bstart persists.
__global__ __launch_bounds__(512) void bscan_kernel(const int* __restrict__ bcnt,
                                                    int* __restrict__ bcursor,
                                                    int* __restrict__ bstart, int B) {
    __shared__ int sh[512];
    const int t = threadIdx.x;
    int v = (t < B) ? bcnt[t] : 0;
    sh[t] = v;
    __syncthreads();
    for (int d = 1; d < 512; d <<= 1) {
        int u = (t >= d) ? sh[t - d] : 0;
        __syncthreads();
        sh[t] += u;
        __syncthreads();
    }
    if (t < B) {
        int excl = sh[t] - v;
        bcursor[t] = excl;
        bstart[t] = excl;
    }
    if (t == B - 1) bstart[B] = sh[t];
}

// Partition edges into dst-buckets. Packed: src (24 bits) | local-dst (8 bits).
__global__ __launch_bounds__(256) void bscatter_kernel(const int* __restrict__ src,
                                                       const int* __restrict__ dst,
                                                       int* __restrict__ bcursor,
                                                       unsigned* __restrict__ pairs,
                                                       int E, int B) {
    __shared__ int h[BMAX];
    __shared__ int base[BMAX];
    const int t = threadIdx.x;
    for (int i = t; i < B; i += 256) h[i] = 0;
    __syncthreads();
    const int chunk = (E + gridDim.x - 1) / gridDim.x;
    const int e0 = blockIdx.x * chunk;
    const int e1 = min(e0 + chunk, E);
    for (int e = e0 + t; e < e1; e += 256)
        atomicAdd(&h[dst[e] >> BSHIFT], 1);
    __syncthreads();
    for (int i = t; i < B; i += 256) {
        int c = h[i];
        base[i] = c ? atomicAdd(&bcursor[i], c) : 0;
    }
    __syncthreads();
    for (int i = t; i < B; i += 256) h[i] = base[i];
    __syncthreads();
    for (int e = e0 + t; e < e1; e += 256) {
        int d = dst[e];
        int pos = atomicAdd(&h[d >> BSHIFT], 1);
        pairs[pos] = (unsigned)src[e] | ((unsigned)(d & BMASK) << 24);
    }
}

// ---------------------------------------------------------------------------
// Per-bucket finalize: histogram 256 local dsts -> LDS scan -> node offsets +
// scatter src into csr. All atomics in LDS; csr writes land in a contiguous
// per-bucket window.
// ---------------------------------------------------------------------------
__global__ __launch_bounds__(256) void bfinal_kernel(const unsigned* __restrict__ pairs,
                                                     const int* __restrict__ bstart,
                                                     int* __restrict__ offsets,
                                                     int* __restrict__ csr,
                                                     int N, int E) {
    __shared__ int h[256];
    __shared__ int cur[256];
    const int b = blockIdx.x;
    const int t = threadIdx.x;
    const int e0 = bstart[b], e1 = bstart[b + 1];
    h[t] = 0;
    __syncthreads();
    for (int e = e0 + t; e < e1; e += 256)
        atomicAdd(&h[pairs[e] >> 24], 1);
    __syncthreads();
    int v = h[t];
    for (int d = 1; d < 256; d <<= 1) {
        int u = (t >= d) ? h[t - d] : 0;
        __syncthreads();
        h[t] += u;
        __syncthreads();
    }
    const int base = e0 + (h[t] - v);   // exclusive prefix within bucket
    const int node = (b << BSHIFT) + t;
    if (node < N) offsets[node] = base;
    if (b == (int)gridDim.x - 1 && t == 255) offsets[N] = E;
    cur[t] = base;
    __syncthreads();
    for (int e = e0 + t; e < e1; e += 256) {
        unsigned pr = pairs[e];
        int pos = atomicAdd(&cur[pr >> 24], 1);
        csr[pos] = (int)(pr & 0xFFFFFFu);
    }
}

// ---------------------------------------------------------------------------
// Aggregate: Hb[n][:] = bf16( (xb[n][:] + sum_neighbors xb[s][:]) / (deg+1) )
//
// One wave per node; 4 lane-groups of 16, each group gathers one full 256B
// row per load instruction. COMPILER-PROOF deep pipeline: 8 round-gathers +
// tail + self are issued as inline-asm global_load_dwordx4 (volatile => the
// scheduler cannot re-serialize them to shrink live ranges, which it did to
// every C-level formulation: VGPR stayed 16/24/36 across rounds 1-3).
// Branch-free: indices CLAMPED into [start..end-1] (junk slots re-hit a hot
// line -> no extra beyond-L2 traffic), consume AND-masks invalid slots to
// +0.0f. Explicit s_waitcnt vmcnt(0) + sched_barrier(0) fences (rule #18).
// deg > 32 falls back to a plain loop (P ~ 1e-4 at avg deg 16).
// ---------------------------------------------------------------------------
static __device__ inline f32x2 up2(unsigned u) {
    return (f32x2){ b2f_lo(u), b2f_hi(u) };
}

#define GATHER(dst, off) \
    asm volatile("global_load_dwordx4 %0, %1, %2" : "=v"(dst) : "v"(off), "s"(xc))
#define ACCM(u, mk) do { \
    A0 += up2((u).x & (mk)); A1 += up2((u).y & (mk)); \
    A2 += up2((u).z & (mk)); A3 += up2((u).w & (mk)); } while (0)

__global__ __launch_bounds__(256) void aggregate_kernel(const unsigned short* __restrict__ xb,
                                                        const int* __restrict__ offsets,
                                                        const int* __restrict__ csr,
                                                        unsigned short* __restrict__ Hb,
                                                        int N) {
    const int node = (blockIdx.x * blockDim.x + threadIdx.x) >> 6;
    if (node >= N) return;
    const int lane = threadIdx.x & 63;
    const int g = lane >> 4;                              // neighbor slot 0..3
    const unsigned poff = (unsigned)((lane & 15) << 4);   // 16B chunk in row
    const int start = offsets[node];
    const int end   = offsets[node + 1];
    const int deg   = end - start;
    const int rounds = deg >> 2;
    const int tailn  = deg & 3;
    const char* __restrict__ xc = (const char*)xb;

    // ---- self gather: issued first, consumed last ----
    const unsigned soff = ((unsigned)node << 8) | poff;
    u32x4 vs;
    GATHER(vs, soff);

    // ---- index phase: 9 independent csr loads (positions clamped in-window;
    //      deg==0 reads csr[-1] == bstart[B], still inside the workspace) ----
    const int jmax = end - 1;
    unsigned o0, o1, o2, o3, o4, o5, o6, o7, ot;
#define CIDX(dsto, r) do { \
        int j = start + ((r) << 2) + g; j = j > jmax ? jmax : j; \
        int s = csr[j]; s = min(max(s, 0), N - 1); \
        dsto = ((unsigned)s << 8) | poff; } while (0)
    CIDX(o0, 0); CIDX(o1, 1); CIDX(o2, 2); CIDX(o3, 3);
    CIDX(o4, 4); CIDX(o5, 5); CIDX(o6, 6); CIDX(o7, 7);
    { int j = start + (rounds << 2) + g; j = j > jmax ? jmax : j;
      j = j < 0 ? 0 : j;
      int s = csr[j]; s = min(max(s, 0), N - 1);
      ot = ((unsigned)s << 8) | poff; }
#undef CIDX

    const unsigned m0 = rounds >= 1 ? ~0u : 0u;
    const unsigned m1 = rounds >= 2 ? ~0u : 0u;
    const unsigned m2 = rounds >= 3 ? ~0u : 0u;
    const unsigned m3 = rounds >= 4 ? ~0u : 0u;
    const unsigned m4 = rounds >= 5 ? ~0u : 0u;
    const unsigned m5 = rounds >= 6 ? ~0u : 0u;
    const unsigned m6 = rounds >= 7 ? ~0u : 0u;
    const unsigned m7 = rounds >= 8 ? ~0u : 0u;
    const unsigned mt = g < tailn ? ~0u : 0u;

    __builtin_amdgcn_sched_barrier(0);   // index phase fully before gather issue

    // ---- issue phase: 9 gathers back-to-back, all in flight ----
    u32x4 v0, v1, v2, v3, v4, v5, v6, v7, vt;
    GATHER(v0, o0); GATHER(v1, o1); GATHER(v2, o2); GATHER(v3, o3);
    GATHER(v4, o4); GATHER(v5, o5); GATHER(v6, o6); GATHER(v7, o7);
    GATHER(vt, ot);
    asm volatile("s_waitcnt vmcnt(0)" ::: "memory");
    __builtin_amdgcn_sched_barrier(0);   // consumes cannot hoist above the wait

    // ---- consume phase ----
    f32x2 A0 = {0.f, 0.f}, A1 = {0.f, 0.f}, A2 = {0.f, 0.f}, A3 = {0.f, 0.f};
    ACCM(v0, m0); ACCM(v1, m1); ACCM(v2, m2); ACCM(v3, m3);
    ACCM(v4, m4); ACCM(v5, m5); ACCM(v6, m6); ACCM(v7, m7);
    ACCM(vt, mt);
    for (int r = 8; r < rounds; ++r) {   // deg > 35: vanishingly rare
        int s = csr[start + (r << 2) + g];
        s = min(max(s, 0), N - 1);
        u32x4 u = *(const u32x4*)(xc + (((unsigned)s << 8) | poff));
        ACCM(u, ~0u);
    }

    // combine the 4 lane-groups: butterfly leaves full sum in every lane
    float a[8];
    a[0] = A0.x; a[1] = A0.y; a[2] = A1.x; a[3] = A1.y;
    a[4] = A2.x; a[5] = A2.y; a[6] = A3.x; a[7] = A3.y;
#pragma unroll
    for (int i = 0; i < 8; ++i) {
        a[i] += __shfl_xor(a[i], 16);
        a[i] += __shfl_xor(a[i], 32);
    }
    // self term (post-reduce, added once)
    a[0] += b2f_lo(vs.x); a[1] += b2f_hi(vs.x);
    a[2] += b2f_lo(vs.y); a[3] += b2f_hi(vs.y);
    a[4] += b2f_lo(vs.z); a[5] += b2f_hi(vs.z);
    a[6] += b2f_lo(vs.w); a[7] += b2f_hi(vs.w);

    const float inv = 1.0f / (float)(deg + 1);
    if (g == 0) {
        uint4 o;
        o.x = (unsigned)f2b(a[0] * inv) | ((unsigned)f2b(a[1] * inv) << 16);
        o.y = (unsigned)f2b(a[2] * inv) | ((unsigned)f2b(a[3] * inv) << 16);
        o.z = (unsigned)f2b(a[4] * inv) | ((unsigned)f2b(a[5] * inv) << 16);
        o.w = (unsigned)f2b(a[6] * inv) | ((unsigned)f2b(a[7] * inv) << 16);
        *(uint4*)((char*)Hb + (((unsigned)node << 8) | poff)) = o;
    }
}

// ---------------------------------------------------------------------------
// MFMA GEMM: out[r][c] = leaky( sum_k H[r][k] * W[k][c] + b[c] )
// 128 rows x 128 cols per block, 256 threads = 4 waves; wave w covers rows
// w*32..w*32+31 as 2 row-tiles x 8 col-tiles of 16x16x32 bf16 MFMA.
// W staged in LDS (reused by all 4 waves, XOR-swizzled, conflict-free b128);
// A-fragments stream STRAIGHT FROM GLOBAL (fully coalesced, used once).
// ---------------------------------------------------------------------------
template <bool OUT_BF16>
__global__ __launch_bounds__(256) void gemm_mfma(const unsigned short* __restrict__ Hb,
                                                 const unsigned short* __restrict__ Wt,
                                                 const float* __restrict__ b,
                                                 void* __restrict__ outv, int N) {
    __shared__ unsigned short Wa[128 * 128];  // 32 KB
    const int tid = threadIdx.x;
    const int row0 = blockIdx.x * 128;

    // Stage Wa (Wt is [n][k] bf16, 2048 16B chunks, swizzled)
#pragma unroll
    for (int it = 0; it < 8; ++it) {
        int idx = it * 256 + tid;
        int r = idx >> 4, c = idx & 15;
        uint4 v = *(const uint4*)(Wt + r * 128 + c * 8);
        *(uint4*)(Wa + r * 128 + ((c ^ (r & 15)) << 3)) = v;
    }
    __syncthreads();

    const int w = tid >> 6;
    const int lane = tid & 63;
    const int m = lane & 15;   // A row-in-tile / B col-in-tile / C col
    const int q = lane >> 4;   // quad

    // A rows for this lane (clamped; OOB rows never stored)
    const int r0 = row0 + w * 32 + m;
    const size_t ar0 = (size_t)min(r0, N - 1) * 128;
    const size_t ar1 = (size_t)min(r0 + 16, N - 1) * 128;

    f32x4 acc[2][8];
#pragma unroll
    for (int rt = 0; rt < 2; ++rt)
#pragma unroll
        for (int ct = 0; ct < 8; ++ct) acc[rt][ct] = (f32x4){0.f, 0.f, 0.f, 0.f};

#pragma unroll
    for (int kk = 0; kk < 4; ++kk) {
        const int chunk = kk * 4 + q;  // this lane's 16B chunk (8 bf16 of k)
        bf16x8 af0 = *(const bf16x8*)(Hb + ar0 + chunk * 8);
        bf16x8 af1 = *(const bf16x8*)(Hb + ar1 + chunk * 8);
#pragma unroll
        for (int ct = 0; ct < 8; ++ct) {
            int n = ct * 16 + m;
            bf16x8 bfr = *(const bf16x8*)(Wa + n * 128 + ((chunk ^ (n & 15)) << 3));
            acc[0][ct] = __builtin_amdgcn_mfma_f32_16x16x32_bf16(af0, bfr, acc[0][ct], 0, 0, 0);
            acc[1][ct] = __builtin_amdgcn_mfma_f32_16x16x32_bf16(af1, bfr, acc[1][ct], 0, 0, 0);
        }
    }

    // Epilogue: bias + leaky-relu, store (fp32 or bf16)
#pragma unroll
    for (int ct = 0; ct < 8; ++ct) {
        const float bias = b[ct * 16 + m];
        const int gcol = ct * 16 + m;
#pragma unroll
        for (int rt = 0; rt < 2; ++rt) {
#pragma unroll
            for (int reg = 0; reg < 4; ++reg) {
                int grow = row0 + w * 32 + rt * 16 + q * 4 + reg;
                if (grow < N) {
                    float v = acc[rt][ct][reg] + bias;
                    v = v > 0.f ? v : v * NEG_SLOPE;
                    if (OUT_BF16)
                        ((unsigned short*)outv)[(long long)grow * 128 + gcol] = f2b(v);
                    else
                        ((float*)outv)[(long long)grow * 128 + gcol] = v;
                }
            }
        }
    }
}

extern "C" void kernel_launch(void* const* d_in, const int* in_sizes, int n_in,
                              void* d_out, int out_size, void* d_ws, size_t ws_size,
                              hipStream_t stream) {
    const float* feat = (const float*)d_in[0];
    const int*   edges = (const int*)d_in[1];
    const float* W1 = (const float*)d_in[2];
    const float* b1 = (const float*)d_in[3];
    const float* W2 = (const float*)d_in[4];
    const float* b2 = (const float*)d_in[5];
    float* out = (float*)d_out;

    const int N = in_sizes[0] / 128;
    const int E = in_sizes[1] / 2;
    const int* src = edges;
    const int* dst = edges + E;
    const int B = (N + (1 << BSHIFT) - 1) >> BSHIFT;

    // Workspace layout (all 16B-aligned):
    //   featb:  N*128 bf16 (25.6 MB) — feat bf16; REUSED as h1b after aggregate-1
    //   Hb:     N*128 bf16 (25.6 MB) — aggregated features; pairs (E uint) aliased
    //   Wt1,Wt2: 128*128 bf16 each
    //   offsets/bcnt/bcursor/bstart/csr: ints
    unsigned short* featb = (unsigned short*)d_ws;
    unsigned short* Hb    = featb + (size_t)N * 128;
    unsigned*       pairs = (unsigned*)Hb;          // dead before aggregate-1
    unsigned short* Wt1   = Hb + (size_t)N * 128;
    unsigned short* Wt2   = Wt1 + 128 * 128;
    int* offsets = (int*)(Wt2 + 128 * 128);
    int* bcnt    = offsets + (N + 1);
    int* bcursor = bcnt + B;
    int* bstart  = bcursor + B;
    int* csr     = bstart + (B + 1);

    // ---- dtype conversions (independent of CSR build); cvt_w zeroes bcnt ----
    long long nfeat = (long long)N * 128;
    cvt_feat<<<(int)((nfeat / 4 + 255) / 256), 256, 0, stream>>>(feat, featb, nfeat);
    cvt_w<<<64, 256, 0, stream>>>(W1, W2, Wt1, Wt2, bcnt, B);

    // ---- Build CSR (dst -> list of src) via bucket radix ----
    bhist_kernel<<<256, 256, 0, stream>>>(dst, bcnt, E, B);
    bscan_kernel<<<1, 512, 0, stream>>>(bcnt, bcursor, bstart, B);
    bscatter_kernel<<<256, 256, 0, stream>>>(src, dst, bcursor, pairs, E, B);
    bfinal_kernel<<<B, 256, 0, stream>>>(pairs, bstart, offsets, csr, N, E);

    const int aggGrid = (N + 3) / 4;
    const int gemmGrid = (N + 127) / 128;

    // ---- Layer 1: aggregate bf16 -> Hb; GEMM writes h1 bf16 into featb ----
    aggregate_kernel<<<aggGrid, 256, 0, stream>>>(featb, offsets, csr, Hb, N);
    gemm_mfma<true><<<gemmGrid, 256, 0, stream>>>(Hb, Wt1, b1, (void*)featb, N);

    // ---- Layer 2: aggregate h1b -> Hb; GEMM writes fp32 to d_out ----
    aggregate_kernel<<<aggGrid, 256, 0, stream>>>(featb, offsets, csr, Hb, N);
    gemm_mfma<false><<<gemmGrid, 256, 0, stream>>>(Hb, Wt2, b2, (void*)out, N);
}